// Round 1
// baseline (1621.154 us; speedup 1.0000x reference)
//
#include <hip/hip_runtime.h>
#include <math.h>

// Problem constants
#define TT 32
#define BB 128
#define DD 256
#define HH 768
#define MAXP 8

// Decomposition: 8 groups x (16 rows), each group = 32 blocks x (24-wide H slice)
#define NG  8
#define RPG 16
#define NBG 32
#define CS  24
#define NTH 512

#define OFF_LAST  ((size_t)TT * BB * HH)
#define OFF_PCOST (OFF_LAST + (size_t)BB * HH)
#define OFF_STEPS (OFF_PCOST + BB)

#define ASCOPE __HIP_MEMORY_SCOPE_AGENT

#define D4(acc, W, Hv) acc += (W).x*(Hv).x + (W).y*(Hv).y + (W).z*(Hv).z + (W).w*(Hv).w

__launch_bounds__(NTH)
__global__ void act_kernel(const float* __restrict__ x,
                           const float* __restrict__ Wih,
                           const float* __restrict__ Whh,
                           const float* __restrict__ bih,
                           const float* __restrict__ bhh,
                           const float* __restrict__ wpv,
                           const float* __restrict__ bp,
                           float* __restrict__ out,
                           unsigned* __restrict__ cnt,
                           float* __restrict__ hxbuf,
                           float* __restrict__ zpart)
{
    const int tid = threadIdx.x;
    const int g   = blockIdx.x & 7;    // group -> XCD (perf heuristic only)
    const int ib  = blockIdx.x >> 3;   // block index within group [0,32)
    const int r0  = g * RPG;           // first batch row of this group
    const int c0  = ib * CS;           // first H column of this block

    // LDS: ~151.5 KB total (1 block/CU)
    __shared__ float Whh_s[CS][772];       // W_hh slice, padded stride
    __shared__ float cur_s[RPG][HH];       // current hx (full rows, local copy)
    __shared__ float part_s[CS][RPG][17];  // j-partials (padded)
    __shared__ float xi_s[RPG][CS];        // per-t input contribution
    __shared__ float hxn_s[RPG][CS];       // new hx slice
    __shared__ float zred_s[RPG][NBG];     // gathered z partials
    __shared__ float ah_s[RPG], spc_s[RPG], pc_s[RPG], w1p_s[RPG], sc_s[RPG];
    __shared__ int   act_s[RPG];
    __shared__ int   nact_s;
    __shared__ float bias_s[CS], wflag_s[CS], wp_s[CS];
    __shared__ float bp_s;

    // matvec tiling coords: tile = 3c x 4r, 16 j-ranges of 48
    const int c3 = tid & 7;
    const int r4 = (tid >> 3) & 3;
    const int jq = tid >> 5;           // [0,16)
    const int cb = c3 * 3;
    const int rb = r4 * 4;
    // combine coords (tid < 384)
    const int orr = tid / CS;
    const int occ = tid % CS;
    // accum_hx ownership: 24 floats per thread
    const int ar = tid >> 5;           // row [0,16)
    const int aq = tid & 31;           // chunk [0,32), 24 floats each

    // ---- stage W_hh slice into LDS ----
    for (int k = tid; k < CS * 192; k += NTH) {
        int row = k / 192, f4 = k % 192;
        float4 v = ((const float4*)(Whh + (size_t)(c0 + row) * HH))[f4];
        *(float4*)&Whh_s[row][f4 * 4] = v;
    }
    if (tid < CS) {
        bias_s[tid]  = bih[c0 + tid] + bhh[c0 + tid];
        wflag_s[tid] = Wih[(size_t)(c0 + tid) * (DD + 1) + DD];  // ponder-flag column
        wp_s[tid]    = wpv[c0 + tid];
    }
    if (tid == 0) bp_s = bp[0];
    if (tid < RPG) pc_s[tid] = 0.f;
    for (int k = tid; k < RPG * 192; k += NTH) {
        int row = k / 192, f4 = k % 192;
        *(float4*)&cur_s[row][f4 * 4] = make_float4(0.f, 0.f, 0.f, 0.f);
    }
    __syncthreads();

    float ahx[24];
    unsigned it = 0;   // global barrier-phase counter (monotone)

    for (int t = 0; t < TT; ++t) {
        // ---- xi = x_t @ Wih[:, :D].T + b_ih + b_hh (own slice) ----
        {
            float a[12];
            #pragma unroll
            for (int q = 0; q < 12; ++q) a[q] = 0.f;
            const float* xb = x + ((size_t)t * BB + r0) * DD;
            #pragma unroll
            for (int dd = 0; dd < 16; dd += 4) {
                const int d = jq * 16 + dd;
                float4 xr0 = *(const float4*)(xb + (size_t)(rb + 0) * DD + d);
                float4 xr1 = *(const float4*)(xb + (size_t)(rb + 1) * DD + d);
                float4 xr2 = *(const float4*)(xb + (size_t)(rb + 2) * DD + d);
                float4 xr3 = *(const float4*)(xb + (size_t)(rb + 3) * DD + d);
                #pragma unroll
                for (int tc = 0; tc < 3; ++tc) {
                    const float* wr = Wih + (size_t)(c0 + cb + tc) * (DD + 1) + d;
                    float w0 = wr[0], w1 = wr[1], w2 = wr[2], w3 = wr[3];
                    a[tc*4+0] += w0*xr0.x + w1*xr0.y + w2*xr0.z + w3*xr0.w;
                    a[tc*4+1] += w0*xr1.x + w1*xr1.y + w2*xr1.z + w3*xr1.w;
                    a[tc*4+2] += w0*xr2.x + w1*xr2.y + w2*xr2.z + w3*xr2.w;
                    a[tc*4+3] += w0*xr3.x + w1*xr3.y + w2*xr3.z + w3*xr3.w;
                }
            }
            #pragma unroll
            for (int tc = 0; tc < 3; ++tc)
                #pragma unroll
                for (int tr = 0; tr < 4; ++tr)
                    part_s[cb + tc][rb + tr][jq] = a[tc*4+tr];
        }
        __syncthreads();
        if (tid < RPG * CS) {
            float s = 0.f;
            #pragma unroll
            for (int q = 0; q < 16; ++q) s += part_s[occ][orr][q];
            xi_s[orr][occ] = s + bias_s[occ];
        }
        if (tid < RPG) {
            ah_s[tid] = 0.f; spc_s[tid] = 0.f; sc_s[tid] = 0.f; act_s[tid] = 1;
        }
        #pragma unroll
        for (int q = 0; q < 24; ++q) ahx[q] = 0.f;
        __syncthreads();

        // ---- ponder loop ----
        int pk = 0;
        for (;;) {
            const unsigned par = it & 1u;   // double-buffer parity

            // matvec partials: cur_s @ Whh_s(slice)^T
            {
                float a[12];
                #pragma unroll
                for (int q = 0; q < 12; ++q) a[q] = 0.f;
                const float* wr0 = &Whh_s[cb + 0][jq * 48];
                const float* wr1 = &Whh_s[cb + 1][jq * 48];
                const float* wr2 = &Whh_s[cb + 2][jq * 48];
                const float* hr0 = &cur_s[rb + 0][jq * 48];
                const float* hr1 = &cur_s[rb + 1][jq * 48];
                const float* hr2 = &cur_s[rb + 2][jq * 48];
                const float* hr3 = &cur_s[rb + 3][jq * 48];
                #pragma unroll
                for (int j = 0; j < 48; j += 4) {
                    float4 ww0 = *(const float4*)(wr0 + j);
                    float4 ww1 = *(const float4*)(wr1 + j);
                    float4 ww2 = *(const float4*)(wr2 + j);
                    float4 hh0 = *(const float4*)(hr0 + j);
                    float4 hh1 = *(const float4*)(hr1 + j);
                    float4 hh2 = *(const float4*)(hr2 + j);
                    float4 hh3 = *(const float4*)(hr3 + j);
                    D4(a[0],  ww0, hh0); D4(a[1],  ww0, hh1);
                    D4(a[2],  ww0, hh2); D4(a[3],  ww0, hh3);
                    D4(a[4],  ww1, hh0); D4(a[5],  ww1, hh1);
                    D4(a[6],  ww1, hh2); D4(a[7],  ww1, hh3);
                    D4(a[8],  ww2, hh0); D4(a[9],  ww2, hh1);
                    D4(a[10], ww2, hh2); D4(a[11], ww2, hh3);
                }
                #pragma unroll
                for (int tc = 0; tc < 3; ++tc)
                    #pragma unroll
                    for (int tr = 0; tr < 4; ++tr)
                        part_s[cb + tc][rb + tr][jq] = a[tc*4+tr];
            }
            __syncthreads();

            // combine partials, tanh, publish slice (agent scope)
            if (tid < RPG * CS) {
                float s = 0.f;
                #pragma unroll
                for (int q = 0; q < 16; ++q) s += part_s[occ][orr][q];
                float pre = s + xi_s[orr][occ] + (pk ? wflag_s[occ] : 0.f);
                float hv = tanhf(pre);
                hxn_s[orr][occ] = hv;
                __hip_atomic_store(&hxbuf[((size_t)(g*2 + par) * RPG + orr) * HH + c0 + occ],
                                   hv, __ATOMIC_RELAXED, ASCOPE);
            }
            __syncthreads();
            if (tid < RPG) {
                float zp = 0.f;
                #pragma unroll
                for (int cc = 0; cc < CS; ++cc) zp += hxn_s[tid][cc] * wp_s[cc];
                __hip_atomic_store(&zpart[((size_t)(g*2 + par) * NBG + ib) * RPG + tid],
                                   zp, __ATOMIC_RELAXED, ASCOPE);
            }

            // group barrier (monotone phase counter; all waves drained at syncthreads)
            ++it;
            __syncthreads();
            if (tid == 0) {
                __hip_atomic_fetch_add(&cnt[g], 1u, __ATOMIC_RELEASE, ASCOPE);
                const unsigned tgt = (unsigned)NBG * it;
                while (__hip_atomic_load(&cnt[g], __ATOMIC_RELAXED, ASCOPE) < tgt)
                    __builtin_amdgcn_s_sleep(2);
                (void)__hip_atomic_load(&cnt[g], __ATOMIC_ACQUIRE, ASCOPE);
            }
            __syncthreads();

            // gather z partials (fixed order -> bitwise-identical in every block)
            {
                const int rr_ = tid & 15, ii = tid >> 4;
                zred_s[rr_][ii] =
                    __hip_atomic_load(&zpart[((size_t)(g*2 + par) * NBG + ii) * RPG + rr_],
                                      __ATOMIC_RELAXED, ASCOPE);
            }
            __syncthreads();
            if (tid < RPG) {
                float w1p = 0.f;
                if (act_s[tid]) {
                    float z = 0.f;
                    #pragma unroll
                    for (int i2 = 0; i2 < NBG; ++i2) z += zred_s[tid][i2];
                    float h = 1.f / (1.f + expf(-(z + bp_s)));
                    spc_s[tid] = -ah_s[tid];
                    float ah2 = ah_s[tid] + h;
                    float p = h - fmaxf(ah2 - 1.f, 0.f);
                    w1p = 1.f + p;
                    sc_s[tid] += 1.f;
                    ah_s[tid] = ah2;
                    act_s[tid] = (ah2 < 0.99f) ? 1 : 0;   // 1-EPS rounds to 0.99f exactly
                }
                w1p_s[tid] = w1p;
            }
            __syncthreads();

            // read full rows, update local hx copy + register accum_hx
            {
                const float w1 = w1p_s[ar];
                const float* src = &hxbuf[((size_t)(g*2 + par) * RPG + ar) * HH + aq * 24];
                float v[24];
                #pragma unroll
                for (int q = 0; q < 24; ++q) {
                    v[q] = __hip_atomic_load(src + q, __ATOMIC_RELAXED, ASCOPE);
                    ahx[q] += w1 * v[q];
                }
                #pragma unroll
                for (int q4 = 0; q4 < 6; ++q4)
                    *(float4*)&cur_s[ar][aq * 24 + q4 * 4] =
                        make_float4(v[q4*4], v[q4*4+1], v[q4*4+2], v[q4*4+3]);
            }
            if (tid == 0) {
                int n = 0;
                #pragma unroll
                for (int r2 = 0; r2 < RPG; ++r2) n += act_s[r2];
                nact_s = n;
            }
            ++pk;
            __syncthreads();
            if (nact_s == 0 || pk == MAXP) break;
        }

        // ---- finalize time step: hx_out = accum_hx / sc (sync-free: ahx replicated) ----
        {
            const float inv = 1.f / sc_s[ar];
            const size_t orow = ((size_t)t * BB + r0 + ar) * HH + aq * 24;
            #pragma unroll
            for (int q4 = 0; q4 < 6; ++q4) {
                float4 o = make_float4(ahx[q4*4] * inv, ahx[q4*4+1] * inv,
                                       ahx[q4*4+2] * inv, ahx[q4*4+3] * inv);
                *(float4*)&cur_s[ar][aq * 24 + q4 * 4] = o;
                if (ib == 0) {
                    *(float4*)(out + orow + q4 * 4) = o;
                    if (t == TT - 1)
                        *(float4*)(out + OFF_LAST + (size_t)(r0 + ar) * HH + aq * 24 + q4 * 4) = o;
                }
            }
            if (tid < RPG) {
                pc_s[tid] += spc_s[tid];
                if (ib == 0) out[OFF_STEPS + (size_t)t * BB + r0 + tid] = sc_s[tid];
            }
        }
        __syncthreads();
    }
    if (ib == 0 && tid < RPG) out[OFF_PCOST + r0 + tid] = pc_s[tid];
}

extern "C" void kernel_launch(void* const* d_in, const int* in_sizes, int n_in,
                              void* d_out, int out_size, void* d_ws, size_t ws_size,
                              hipStream_t stream) {
    const float* x   = (const float*)d_in[0];
    const float* Wih = (const float*)d_in[1];
    const float* Whh = (const float*)d_in[2];
    const float* bih = (const float*)d_in[3];
    const float* bhh = (const float*)d_in[4];
    const float* wpv = (const float*)d_in[5];
    const float* bp  = (const float*)d_in[6];
    float* out = (float*)d_out;

    // ws layout: [0,4096) barrier counters (zeroed every call; harness poisons ws)
    //            [4096, +786432) hx exchange (double-buffered per group)
    //            then z partials (double-buffered per group)
    unsigned* cnt  = (unsigned*)d_ws;
    float*    hxb  = (float*)((char*)d_ws + 4096);
    float*    zpt  = (float*)((char*)d_ws + 4096 + (size_t)NG * 2 * RPG * HH * 4);

    hipMemsetAsync(d_ws, 0, 4096, stream);
    act_kernel<<<dim3(NG * NBG), dim3(NTH), 0, stream>>>(
        x, Wih, Whh, bih, bhh, wpv, bp, out, cnt, hxb, zpt);
}

// Round 2
// 1263.257 us; speedup vs baseline: 1.2833x; 1.2833x over previous
//
#include <hip/hip_runtime.h>
#include <math.h>

// Problem constants
#define TT 32
#define BB 128
#define DD 256
#define HH 768
#define MAXP 8

// Decomposition: 8 groups x (16 rows), each group = 32 blocks x (24-wide H slice)
#define NG  8
#define RPG 16
#define NBG 32
#define CS  24
#define NTH 512
#define SW  772   // LDS row stride (floats): 772 ≡ 4 mod 32 banks

#define OFF_LAST  ((size_t)TT * BB * HH)
#define OFF_PCOST (OFF_LAST + (size_t)BB * HH)
#define OFF_STEPS (OFF_PCOST + BB)

#define ASCOPE __HIP_MEMORY_SCOPE_AGENT

typedef __attribute__((ext_vector_type(2))) float f32x2;

#define D4(acc, W, Hv) acc += (W).x*(Hv).x + (W).y*(Hv).y + (W).z*(Hv).z + (W).w*(Hv).w

__launch_bounds__(NTH, 1)
__global__ void act_kernel(const float* __restrict__ x,
                           const float* __restrict__ Wih,
                           const float* __restrict__ Whh,
                           const float* __restrict__ bih,
                           const float* __restrict__ bhh,
                           const float* __restrict__ wpv,
                           const float* __restrict__ bp,
                           float* __restrict__ out,
                           unsigned* __restrict__ flags,
                           float* __restrict__ hxbuf,
                           float* __restrict__ zpart)
{
    const int tid = threadIdx.x;
    const int g   = blockIdx.x & 7;    // group -> XCD (perf heuristic only)
    const int ib  = blockIdx.x >> 3;   // block index within group [0,32)
    const int r0  = g * RPG;
    const int c0  = ib * CS;

    // LDS ~151.5 KB -> 1 block/CU
    __shared__ float Whh_s[CS][SW];        // 74112 B
    __shared__ float cur_s[RPG][SW];       // 49408 B
    __shared__ float part_s[16][RPG][25];  // 25600 B  [jq][row][col]
    __shared__ float xi_s[RPG][CS];
    __shared__ float hxn_s[RPG][25];
    __shared__ float zred_s[RPG][33];
    __shared__ float ah_s[RPG], spc_s[RPG], pc_s[RPG], w1p_s[RPG], sc_s[RPG], inv_s[RPG];
    __shared__ int   act_s[RPG];
    __shared__ int   nact_s;
    __shared__ float bias_s[CS], wflag_s[CS], wp_s[CS];
    __shared__ float bp_s;

    // matvec tiling: cols cb..cb+2 ; rows {r4, r4+4, r4+8, r4+12} (stride-4 ->
    // across-lane row banksets {0,4,8,12} with SW=772 -> conflict-free hh reads)
    const int c3 = tid & 7;
    const int r4 = (tid >> 3) & 3;
    const int jq = tid >> 5;           // k-range [jq*48, jq*48+48)
    const int cb = c3 * 3;
    // combine coords (tid < 384)
    const int orr = tid / CS;
    const int occ = tid % CS;

    // ---- stage W_hh slice ----
    for (int k = tid; k < CS * 192; k += NTH) {
        int row = k / 192, f4 = k % 192;
        float4 v = ((const float4*)(Whh + (size_t)(c0 + row) * HH))[f4];
        *(float4*)&Whh_s[row][f4 * 4] = v;
    }
    if (tid < CS) {
        bias_s[tid]  = bih[c0 + tid] + bhh[c0 + tid];
        wflag_s[tid] = Wih[(size_t)(c0 + tid) * (DD + 1) + DD];
        wp_s[tid]    = wpv[c0 + tid];
    }
    if (tid == 0) bp_s = bp[0];
    if (tid < RPG) pc_s[tid] = 0.f;
    for (int k = tid; k < RPG * 193; k += NTH) {
        int row = k / 193, f4 = k % 193;
        *(float4*)&cur_s[row][f4 * 4] = make_float4(0.f, 0.f, 0.f, 0.f);
    }
    __syncthreads();

    float ahx[24];
    unsigned it = 0;   // monotone barrier-phase counter

    for (int t = 0; t < TT; ++t) {
        // ---- xi = x_t @ Wih[:, :D].T + b (own slice) ----
        {
            float a[12];
            #pragma unroll
            for (int q = 0; q < 12; ++q) a[q] = 0.f;
            const float* xb = x + ((size_t)t * BB + r0) * DD;
            #pragma unroll
            for (int dd = 0; dd < 16; dd += 4) {
                const int d = jq * 16 + dd;
                float4 xr0 = *(const float4*)(xb + (size_t)(r4 +  0) * DD + d);
                float4 xr1 = *(const float4*)(xb + (size_t)(r4 +  4) * DD + d);
                float4 xr2 = *(const float4*)(xb + (size_t)(r4 +  8) * DD + d);
                float4 xr3 = *(const float4*)(xb + (size_t)(r4 + 12) * DD + d);
                #pragma unroll
                for (int tc = 0; tc < 3; ++tc) {
                    const float* wr = Wih + (size_t)(c0 + cb + tc) * (DD + 1) + d;
                    float w0 = wr[0], w1 = wr[1], w2 = wr[2], w3 = wr[3];
                    a[tc*4+0] += w0*xr0.x + w1*xr0.y + w2*xr0.z + w3*xr0.w;
                    a[tc*4+1] += w0*xr1.x + w1*xr1.y + w2*xr1.z + w3*xr1.w;
                    a[tc*4+2] += w0*xr2.x + w1*xr2.y + w2*xr2.z + w3*xr2.w;
                    a[tc*4+3] += w0*xr3.x + w1*xr3.y + w2*xr3.z + w3*xr3.w;
                }
            }
            #pragma unroll
            for (int tc = 0; tc < 3; ++tc)
                #pragma unroll
                for (int k = 0; k < 4; ++k)
                    part_s[jq][k*4 + r4][cb + tc] = a[tc*4 + k];
        }
        __syncthreads();
        if (tid < RPG * CS) {
            float s = 0.f;
            #pragma unroll
            for (int q = 0; q < 16; ++q) s += part_s[q][orr][occ];
            xi_s[orr][occ] = s + bias_s[occ];
        }
        if (tid < RPG) {
            ah_s[tid] = 0.f; spc_s[tid] = 0.f; sc_s[tid] = 0.f; act_s[tid] = 1;
        }
        #pragma unroll
        for (int q = 0; q < 24; ++q) ahx[q] = 0.f;
        __syncthreads();

        // ---- ponder loop ----
        int pk = 0;
        for (;;) {
            const unsigned par = it & 1u;
            float* hb = hxbuf + (size_t)(g*2 + par) * (RPG * HH);

            // matvec partials: cur_s @ Whh_s(slice)^T
            {
                float a[12];
                #pragma unroll
                for (int q = 0; q < 12; ++q) a[q] = 0.f;
                const float* wr0 = &Whh_s[cb + 0][jq * 48];
                const float* wr1 = &Whh_s[cb + 1][jq * 48];
                const float* wr2 = &Whh_s[cb + 2][jq * 48];
                const float* hr0 = &cur_s[r4 +  0][jq * 48];
                const float* hr1 = &cur_s[r4 +  4][jq * 48];
                const float* hr2 = &cur_s[r4 +  8][jq * 48];
                const float* hr3 = &cur_s[r4 + 12][jq * 48];
                #pragma unroll
                for (int j = 0; j < 48; j += 4) {
                    float4 ww0 = *(const float4*)(wr0 + j);
                    float4 ww1 = *(const float4*)(wr1 + j);
                    float4 ww2 = *(const float4*)(wr2 + j);
                    float4 hh0 = *(const float4*)(hr0 + j);
                    float4 hh1 = *(const float4*)(hr1 + j);
                    float4 hh2 = *(const float4*)(hr2 + j);
                    float4 hh3 = *(const float4*)(hr3 + j);
                    D4(a[0],  ww0, hh0); D4(a[1],  ww0, hh1);
                    D4(a[2],  ww0, hh2); D4(a[3],  ww0, hh3);
                    D4(a[4],  ww1, hh0); D4(a[5],  ww1, hh1);
                    D4(a[6],  ww1, hh2); D4(a[7],  ww1, hh3);
                    D4(a[8],  ww2, hh0); D4(a[9],  ww2, hh1);
                    D4(a[10], ww2, hh2); D4(a[11], ww2, hh3);
                }
                #pragma unroll
                for (int tc = 0; tc < 3; ++tc)
                    #pragma unroll
                    for (int k = 0; k < 4; ++k)
                        part_s[jq][k*4 + r4][cb + tc] = a[tc*4 + k];
            }
            __syncthreads();

            // combine, tanh, publish slice
            if (tid < RPG * CS) {
                float s = 0.f;
                #pragma unroll
                for (int q = 0; q < 16; ++q) s += part_s[q][orr][occ];
                float pre = s + xi_s[orr][occ] + (pk ? wflag_s[occ] : 0.f);
                float hv = tanhf(pre);
                hxn_s[orr][occ] = hv;
                __hip_atomic_store(&hb[(size_t)orr * HH + c0 + occ], hv,
                                   __ATOMIC_RELAXED, ASCOPE);
            }
            __syncthreads();
            if (tid < RPG) {
                float zp = 0.f;
                #pragma unroll
                for (int cc = 0; cc < CS; ++cc) zp += hxn_s[tid][cc] * wp_s[cc];
                __hip_atomic_store(&zpart[((size_t)(g*2 + par) * NBG + ib) * RPG + tid],
                                   zp, __ATOMIC_RELAXED, ASCOPE);
            }

            // flag-vector barrier: syncthreads drains all waves' stores (vmcnt0),
            // then one relaxed flag store; wave0 polls all 32 flags coalesced.
            ++it;
            __syncthreads();
            if (tid < 64) {
                if (tid == 0)
                    __hip_atomic_store(&flags[g * NBG + ib], it, __ATOMIC_RELAXED, ASCOPE);
                unsigned v;
                do {
                    v = __hip_atomic_load(&flags[g * NBG + (tid & 31)],
                                          __ATOMIC_RELAXED, ASCOPE);
                } while (!__all((int)(v >= it)));
                __builtin_amdgcn_fence(__ATOMIC_ACQUIRE, "agent");
            }
            __syncthreads();

            // coalesced full-group hx read (12 b64/thread), issued before z work
            unsigned long long hraw[12];
            {
                const unsigned long long* hb64 = (const unsigned long long*)hb;
                #pragma unroll
                for (int q = 0; q < 12; ++q)
                    hraw[q] = __hip_atomic_load(hb64 + q * 512 + tid,
                                                __ATOMIC_RELAXED, ASCOPE);
            }
            // z gather (fixed order -> bitwise-identical in every block)
            {
                const int rr_ = tid >> 5, i2 = tid & 31;
                zred_s[rr_][i2] =
                    __hip_atomic_load(&zpart[((size_t)(g*2 + par) * NBG + i2) * RPG + rr_],
                                      __ATOMIC_RELAXED, ASCOPE);
            }
            __syncthreads();
            if (tid < RPG) {
                float w1p = 0.f;
                if (act_s[tid]) {
                    float z = 0.f;
                    #pragma unroll
                    for (int i2 = 0; i2 < NBG; ++i2) z += zred_s[tid][i2];
                    float h = 1.f / (1.f + expf(-(z + bp_s)));
                    spc_s[tid] = -ah_s[tid];
                    float ah2 = ah_s[tid] + h;
                    float p = h - fmaxf(ah2 - 1.f, 0.f);
                    w1p = 1.f + p;
                    sc_s[tid] += 1.f;
                    ah_s[tid] = ah2;
                    act_s[tid] = (ah2 < 0.99f) ? 1 : 0;   // 1-EPS == 0.99f exactly
                }
                w1p_s[tid] = w1p;
            }
            __syncthreads();   // syncA

            // update local hx copy + register accum_hx (flat ownership)
            #pragma unroll
            for (int q = 0; q < 12; ++q) {
                const int p  = q * 512 + tid;     // b64 index in [0, 6144)
                const int r  = p / 384;
                const int cc = (p - r * 384) * 2;
                union { unsigned long long u; f32x2 f; } cv; cv.u = hraw[q];
                *(f32x2*)&cur_s[r][cc] = cv.f;
                const float w1 = w1p_s[r];
                ahx[2*q]   += w1 * cv.f.x;
                ahx[2*q+1] += w1 * cv.f.y;
            }
            if (tid == 0) {
                int n = 0;
                #pragma unroll
                for (int r2 = 0; r2 < RPG; ++r2) n += act_s[r2];
                nact_s = n;
            }
            ++pk;
            __syncthreads();   // syncB
            if (nact_s == 0 || pk == MAXP) break;
        }

        // ---- finalize: hx_out = accum_hx / sc (ahx replicated -> sync-free) ----
        if (tid < RPG) {
            inv_s[tid] = 1.f / sc_s[tid];
            pc_s[tid] += spc_s[tid];
            if (ib == 0) out[OFF_STEPS + (size_t)t * BB + r0 + tid] = sc_s[tid];
        }
        __syncthreads();
        #pragma unroll
        for (int q = 0; q < 12; ++q) {
            const int p  = q * 512 + tid;
            const int r  = p / 384;
            const int cc = (p - r * 384) * 2;
            f32x2 o;
            o.x = ahx[2*q]   * inv_s[r];
            o.y = ahx[2*q+1] * inv_s[r];
            *(f32x2*)&cur_s[r][cc] = o;
            if (ib == 0) {
                *(f32x2*)(out + ((size_t)t * BB + r0 + r) * HH + cc) = o;
                if (t == TT - 1)
                    *(f32x2*)(out + OFF_LAST + (size_t)(r0 + r) * HH + cc) = o;
            }
        }
        __syncthreads();
    }
    if (ib == 0 && tid < RPG) out[OFF_PCOST + r0 + tid] = pc_s[tid];
}

extern "C" void kernel_launch(void* const* d_in, const int* in_sizes, int n_in,
                              void* d_out, int out_size, void* d_ws, size_t ws_size,
                              hipStream_t stream) {
    const float* x   = (const float*)d_in[0];
    const float* Wih = (const float*)d_in[1];
    const float* Whh = (const float*)d_in[2];
    const float* bih = (const float*)d_in[3];
    const float* bhh = (const float*)d_in[4];
    const float* wpv = (const float*)d_in[5];
    const float* bp  = (const float*)d_in[6];
    float* out = (float*)d_out;

    // ws: [0,4096) flags (zeroed); [4096,+786432) hx exchange; then z partials
    unsigned* flags = (unsigned*)d_ws;
    float*    hxb   = (float*)((char*)d_ws + 4096);
    float*    zpt   = (float*)((char*)d_ws + 4096 + (size_t)NG * 2 * RPG * HH * 4);

    hipMemsetAsync(d_ws, 0, 4096, stream);
    act_kernel<<<dim3(NG * NBG), dim3(NTH), 0, stream>>>(
        x, Wih, Whh, bih, bhh, wpv, bp, out, flags, hxb, zpt);
}

// Round 3
// 398.055 us; speedup vs baseline: 4.0727x; 3.1736x over previous
//
#include <hip/hip_runtime.h>
#include <math.h>

// Problem constants
#define TT 32
#define BB 128
#define DD 256
#define HH 768
#define MAXP 8

// Decomposition: 8 rowgroups (16 rows) x 12 col-blocks (64 cols), 256 thr (4 waves = 4 col-tiles)
#define RG   8
#define RPG  16
#define CB   12
#define CS   64
#define NTH  256
#define NCH  24    // K chunks of 32

#define OFF_LAST  ((size_t)TT * BB * HH)
#define OFF_PCOST (OFF_LAST + (size_t)BB * HH)
#define OFF_STEPS (OFF_PCOST + BB)

#define ASCOPE __HIP_MEMORY_SCOPE_AGENT

typedef __attribute__((ext_vector_type(8))) short s16x8;
typedef __attribute__((ext_vector_type(4))) float f32x4;
typedef unsigned long long ull;

static __device__ __forceinline__ unsigned short f2bf(float f) {
    unsigned u = __float_as_uint(f);
    u = (u + 0x7fffu + ((u >> 16) & 1u)) >> 16;   // RNE
    return (unsigned short)u;
}
static __device__ __forceinline__ float bf2f(unsigned short h) {
    return __uint_as_float(((unsigned)h) << 16);
}

__launch_bounds__(NTH, 1)
__global__ void act_kernel(const float* __restrict__ x,
                           const float* __restrict__ Wih,
                           const float* __restrict__ Whh,
                           const float* __restrict__ bih,
                           const float* __restrict__ bhh,
                           const float* __restrict__ wpv,
                           const float* __restrict__ bp,
                           float* __restrict__ out,
                           unsigned* __restrict__ flags,
                           ull* __restrict__ hxe,
                           float* __restrict__ zpt)
{
    const int tid  = threadIdx.x;
    const int rg   = blockIdx.x & 7;     // rowgroup -> XCD (perf heuristic only)
    const int cbk  = blockIdx.x >> 3;    // col-block [0,12)
    const int r0   = rg * RPG;
    const int c0   = cbk * CS;
    const int CT   = tid >> 6;           // wave = col-tile [0,4)
    const int lane = tid & 63;
    const int am   = lane & 15;          // A-frag row / C-frag col
    const int aq   = lane >> 4;

    // LDS ~69 KB
    __shared__ s16x8 A_s[NCH * 64];        // selected hx, MFMA A-frag layout (24.5 KB)
    __shared__ s16x8 WB_s[4 * 8 * 64];     // Wih B-frags (32 KB)
    __shared__ s16x8 xA_s[8 * 64];         // x_t A-frags (8 KB)
    __shared__ unsigned short hxn_s[RPG][72];   // new hx slice, bf16 (pad 72)
    __shared__ float zp4_s[RPG][4];
    __shared__ float zred_s[RPG][13];
    __shared__ float ah_s[RPG], spc_s[RPG], pc_s[RPG], w1p_s[RPG], sc_s[RPG], inv_s[RPG];
    __shared__ int   act_s[RPG];
    __shared__ int   nact_s;
    __shared__ float bias_s[CS], wflag_s[CS], wp_s[CS];
    __shared__ float bp_s;

    // ---- init: Whh B-frags -> permanent VGPRs (96) ----
    s16x8 Breg[NCH];
    {
        const float* wr = Whh + (size_t)(c0 + CT*16 + am) * HH + aq*8;
        for (int ch = 0; ch < NCH; ++ch) {
            float4 a0 = *(const float4*)(wr + ch*32);
            float4 a1 = *(const float4*)(wr + ch*32 + 4);
            union { s16x8 v; unsigned short e[8]; } u;
            u.e[0]=f2bf(a0.x); u.e[1]=f2bf(a0.y); u.e[2]=f2bf(a0.z); u.e[3]=f2bf(a0.w);
            u.e[4]=f2bf(a1.x); u.e[5]=f2bf(a1.y); u.e[6]=f2bf(a1.z); u.e[7]=f2bf(a1.w);
            Breg[ch] = u.v;
        }
    }
    // Wih B-frags -> LDS (row stride 257 unaligned: scalar loads, init-only)
    for (int ch = 0; ch < 8; ++ch) {
        const float* wr = Wih + (size_t)(c0 + CT*16 + am) * (DD+1) + ch*32 + aq*8;
        union { s16x8 v; unsigned short e[8]; } u;
        #pragma unroll
        for (int j = 0; j < 8; ++j) u.e[j] = f2bf(wr[j]);
        WB_s[(CT*8 + ch)*64 + lane] = u.v;
    }
    if (tid < CS) {
        bias_s[tid]  = bih[c0+tid] + bhh[c0+tid];
        wflag_s[tid] = Wih[(size_t)(c0+tid)*(DD+1) + DD];   // ponder-flag column
        wp_s[tid]    = wpv[c0+tid];
    }
    if (tid == 0) bp_s = bp[0];
    if (tid < RPG) pc_s[tid] = 0.f;
    {
        s16x8 z8 = {0,0,0,0,0,0,0,0};
        #pragma unroll
        for (int j = 0; j < 6; ++j) A_s[j*NTH + tid] = z8;   // hx0 = 0
    }
    __syncthreads();

    float ahx[48];
    unsigned it = 0;   // monotone barrier-phase counter

    for (int t = 0; t < TT; ++t) {
        // ---- stage x_t slice as bf16 A-frags ----
        #pragma unroll
        for (int j = 0; j < 2; ++j) {
            const int s = j*NTH + tid;       // [0,512): ch = s>>6, lane = s&63 == lane
            const int ch = s >> 6;
            const float* xb = x + ((size_t)t*BB + r0 + am)*DD + ch*32 + aq*8;
            float4 a0 = *(const float4*)xb;
            float4 a1 = *(const float4*)(xb + 4);
            union { s16x8 v; unsigned short e[8]; } u;
            u.e[0]=f2bf(a0.x); u.e[1]=f2bf(a0.y); u.e[2]=f2bf(a0.z); u.e[3]=f2bf(a0.w);
            u.e[4]=f2bf(a1.x); u.e[5]=f2bf(a1.y); u.e[6]=f2bf(a1.z); u.e[7]=f2bf(a1.w);
            xA_s[s] = u.v;
        }
        if (tid < RPG) { ah_s[tid]=0.f; spc_s[tid]=0.f; sc_s[tid]=0.f; act_s[tid]=1; }
        #pragma unroll
        for (int qq = 0; qq < 48; ++qq) ahx[qq] = 0.f;
        __syncthreads();

        // ---- xi tile per wave: x @ Wih^T + bias (MFMA, registers) ----
        f32x4 xi;
        {
            f32x4 acc = {0.f,0.f,0.f,0.f};
            #pragma unroll
            for (int ch = 0; ch < 8; ++ch)
                acc = __builtin_amdgcn_mfma_f32_16x16x32_bf16(
                        xA_s[ch*64 + lane], WB_s[(CT*8 + ch)*64 + lane], acc, 0, 0, 0);
            const float bs = bias_s[CT*16 + am];
            xi[0]=acc[0]+bs; xi[1]=acc[1]+bs; xi[2]=acc[2]+bs; xi[3]=acc[3]+bs;
        }

        // ---- ponder loop ----
        int pk = 0;
        for (;;) {
            const unsigned par = it & 1u;
            ull*   exch = hxe + (size_t)(rg*2 + par) * (NCH*64) * 2;
            float* zpb  = zpt + (size_t)(rg*2 + par) * (CB*16);

            // matvec (MFMA) + tanh -> hxn_s (C-layout: col=lane&15, row=aq*4+reg)
            f32x4 acc = xi;
            #pragma unroll
            for (int ch = 0; ch < NCH; ++ch)
                acc = __builtin_amdgcn_mfma_f32_16x16x32_bf16(
                        A_s[ch*64 + lane], Breg[ch], acc, 0, 0, 0);
            const float fl = pk ? wflag_s[CT*16 + am] : 0.f;
            #pragma unroll
            for (int r = 0; r < 4; ++r)
                hxn_s[aq*4 + r][CT*16 + am] = f2bf(tanhf(acc[r] + fl));
            __syncthreads();   // S1

            // z partials (wave 0, fixed order)
            if (tid < 64) {
                const int r = tid >> 2, cq = tid & 3;
                float s = 0.f;
                #pragma unroll
                for (int i = 0; i < 16; ++i)
                    s += bf2f(hxn_s[r][cq*16 + i]) * wp_s[cq*16 + i];
                zp4_s[r][cq] = s;
            }
            __syncthreads();   // S1b
            if (tid < RPG) {
                const float zp = zp4_s[tid][0] + zp4_s[tid][1] + zp4_s[tid][2] + zp4_s[tid][3];
                __hip_atomic_store(&zpb[cbk*16 + tid], zp, __ATOMIC_RELAXED, ASCOPE);
            }
            // publish new hx slice in A-frag layout (waves 0-1, coalesced)
            if (tid < 128) {
                const int chd = tid >> 6, l = tid & 63;
                const int pm = l & 15, pq = l >> 4;
                const int cbase = chd*32 + pq*8;
                const ull lo = *(const ull*)&hxn_s[pm][cbase];
                const ull hi = *(const ull*)&hxn_s[pm][cbase + 4];
                ull* dst = exch + (size_t)((2*cbk + chd)*64 + l)*2;
                __hip_atomic_store(dst,     lo, __ATOMIC_RELAXED, ASCOPE);
                __hip_atomic_store(dst + 1, hi, __ATOMIC_RELAXED, ASCOPE);
            }

            // rowgroup barrier (12 blocks; syncthreads drains all stores first)
            ++it;
            __syncthreads();   // S2
            if (tid < 64) {
                if (tid == 0)
                    __hip_atomic_store(&flags[rg*16 + cbk], it, __ATOMIC_RELAXED, ASCOPE);
                const int pi = tid % 12;
                unsigned v;
                do { v = __hip_atomic_load(&flags[rg*16 + pi], __ATOMIC_RELAXED, ASCOPE); }
                while (!__all((int)(v >= it)));
                __builtin_amdgcn_fence(__ATOMIC_ACQUIRE, "agent");
            }
            __syncthreads();   // S3

            // staged coalesced read of full new hx (A-frag layout, 24.5 KB/block)
            ull nlo[6], nhi[6];
            #pragma unroll
            for (int j = 0; j < 6; ++j) {
                ull* src = exch + (size_t)(j*NTH + tid)*2;
                nlo[j] = __hip_atomic_load(src,     __ATOMIC_RELAXED, ASCOPE);
                nhi[j] = __hip_atomic_load(src + 1, __ATOMIC_RELAXED, ASCOPE);
            }
            if (tid < 192) {
                const int bb_ = tid >> 4, rr = tid & 15;
                zred_s[rr][bb_] = __hip_atomic_load(&zpb[bb_*16 + rr], __ATOMIC_RELAXED, ASCOPE);
            }
            __syncthreads();   // S4

            // replicated scalar ponder update (bitwise-identical in all 12 blocks)
            if (tid < RPG) {
                float w1p = 0.f;
                if (act_s[tid]) {
                    float z = 0.f;
                    #pragma unroll
                    for (int i2 = 0; i2 < CB; ++i2) z += zred_s[tid][i2];
                    const float h = 1.f / (1.f + expf(-(z + bp_s)));
                    spc_s[tid] = -ah_s[tid];
                    const float ah2 = ah_s[tid] + h;
                    const float p = h - fmaxf(ah2 - 1.f, 0.f);
                    w1p = 1.f + p;
                    sc_s[tid] += 1.f;
                    ah_s[tid] = ah2;
                    act_s[tid] = (ah2 < 0.99f) ? 1 : 0;   // 1-EPS == 0.99f exactly
                }
                w1p_s[tid] = w1p;
            }
            __syncthreads();   // S5

            // accum_hx (replicated, 48 regs) + reader-side selection into A_s
            {
                const float w1 = w1p_s[am];      // slot row == lane&15 for all 6 slots
                const int   aa = act_s[am];
                #pragma unroll
                for (int j = 0; j < 6; ++j) {
                    const ull lo = nlo[j], hi = nhi[j];
                    #pragma unroll
                    for (int i = 0; i < 4; ++i) {
                        ahx[j*8 + i]     += w1 * bf2f((unsigned short)(lo >> (16*i)));
                        ahx[j*8 + 4 + i] += w1 * bf2f((unsigned short)(hi >> (16*i)));
                    }
                    if (aa) {   // frozen rows keep old hx (reference hx_i freeze)
                        union { ull u[2]; s16x8 v; } cv; cv.u[0] = lo; cv.u[1] = hi;
                        A_s[j*NTH + tid] = cv.v;
                    }
                }
            }
            if (tid == 0) {
                int n = 0;
                #pragma unroll
                for (int r2 = 0; r2 < RPG; ++r2) n += act_s[r2];
                nact_s = n;
            }
            ++pk;
            __syncthreads();   // S6
            if (nact_s == 0 || pk == MAXP) break;
        }

        // ---- finalize t: hx_out = accum_hx / sc (ahx replicated -> barrier-free) ----
        if (tid < RPG) {
            inv_s[tid] = 1.f / sc_s[tid];
            pc_s[tid] += spc_s[tid];
            if (cbk == 0) out[OFF_STEPS + (size_t)t*BB + r0 + tid] = sc_s[tid];
        }
        __syncthreads();
        {
            const float inv = inv_s[am];
            #pragma unroll
            for (int j = 0; j < 6; ++j) {
                const int ch = j*4 + CT;
                float o[8];
                #pragma unroll
                for (int i = 0; i < 8; ++i) o[i] = ahx[j*8 + i] * inv;
                union { s16x8 v; unsigned short e[8]; } u;
                #pragma unroll
                for (int i = 0; i < 8; ++i) u.e[i] = f2bf(o[i]);
                A_s[j*NTH + tid] = u.v;   // next t's hx (all blocks, replicated)
                if (cbk == 0) {
                    float* op = out + ((size_t)t*BB + r0 + am)*HH + ch*32 + aq*8;
                    *(float4*)op       = make_float4(o[0], o[1], o[2], o[3]);
                    *(float4*)(op + 4) = make_float4(o[4], o[5], o[6], o[7]);
                    if (t == TT-1) {
                        float* lp = out + OFF_LAST + (size_t)(r0 + am)*HH + ch*32 + aq*8;
                        *(float4*)lp       = make_float4(o[0], o[1], o[2], o[3]);
                        *(float4*)(lp + 4) = make_float4(o[4], o[5], o[6], o[7]);
                    }
                }
            }
        }
        __syncthreads();
    }
    if (cbk == 0 && tid < RPG) out[OFF_PCOST + r0 + tid] = pc_s[tid];
}

extern "C" void kernel_launch(void* const* d_in, const int* in_sizes, int n_in,
                              void* d_out, int out_size, void* d_ws, size_t ws_size,
                              hipStream_t stream) {
    const float* x   = (const float*)d_in[0];
    const float* Wih = (const float*)d_in[1];
    const float* Whh = (const float*)d_in[2];
    const float* bih = (const float*)d_in[3];
    const float* bhh = (const float*)d_in[4];
    const float* wpv = (const float*)d_in[5];
    const float* bp  = (const float*)d_in[6];
    float* out = (float*)d_out;

    // ws: [0,4096) flags (zeroed); [4096,+393216) hx exchange (bf16 A-frag,
    // double-parity per rowgroup); then z partials (6144 B)
    unsigned* flags = (unsigned*)d_ws;
    ull*      hxe   = (ull*)((char*)d_ws + 4096);
    float*    zpt   = (float*)((char*)d_ws + 4096 + (size_t)RG*2*NCH*64*16);

    hipMemsetAsync(d_ws, 0, 4096, stream);
    act_kernel<<<dim3(RG*CB), dim3(NTH), 0, stream>>>(
        x, Wih, Whh, bih, bhh, wpv, bp, out, flags, hxe, zpt);
}